// Round 11
// baseline (604.145 us; speedup 1.0000x reference)
//
#include <hip/hip_runtime.h>
#include <hip/hip_bf16.h>
#include <cstddef>

#define DD 512
#define DKK 64
#define SS 64
#define BS 2048
#define FF 2048
#define VV 8000
#define LL 4
#define BN_SCALE 0.9995003746f
#define FG_KS 64
#define FG_KCH 512

typedef __attribute__((ext_vector_type(8))) short short8;
typedef __attribute__((ext_vector_type(4))) float f32x4;
typedef __hip_bfloat16 bf16;

__device__ __forceinline__ void gload16(const void* g, void* l) {
  __builtin_amdgcn_global_load_lds((const __attribute__((address_space(1))) void*)g,
                                   (__attribute__((address_space(3))) void*)l, 16, 0, 0);
}
__device__ __forceinline__ bf16 tob(float v) { return __float2bfloat16(v); }

struct Params {
  const int* seq; const float* enc; const float* pes; const float* emb;
  const float* sa_wq; const float* sa_bq; const float* sa_wk; const float* sa_bk;
  const float* sa_wv; const float* sa_bv; const float* sa_wo; const float* sa_bo;
  const float* ca_wq; const float* ca_bq; const float* ca_wk; const float* ca_bk;
  const float* ca_wv; const float* ca_bv; const float* ca_wo; const float* ca_bo;
  const float* f_w1; const float* f_b1; const float* f_w2; const float* f_b2;
  const float* bn_g; const float* bn_b; const float* out_w; const float* out_b;
  float* out;
  float* x0; float* x1;
  bf16 *xb0, *xb1, *h, *w1T, *w2T, *qkvTs, *qkvTc, *woTs, *woTc, *encb, *kca, *vtca;
  float* fpart;
};

// ================================================================ prep (+ CA K/V from fp32, blocks 0..127)
__global__ __launch_bounds__(256) void prep_kernel(Params p) {
  __shared__ __align__(16) char smem[18432];
  const int tid = threadIdx.x;

  if (blockIdx.x < 128) {           // CA K/V for all layers (verified R10)
    bf16 (*Ws)[72] = (bf16(*)[72])smem;
    const int w = tid >> 6, lane = tid & 63;
    const int l15 = lane & 15, lhi = lane >> 4;
    const int b = blockIdx.x & 31, i = blockIdx.x >> 5;
    const float* Wk = p.ca_wk + (size_t)i * DD * DKK;
    const float* Wv = p.ca_wv + (size_t)i * DD * DKK;
    f32x4 acc[8] = {};
    for (int kc = 0; kc < DD; kc += 64) {
      __syncthreads();
#pragma unroll
      for (int j = 0; j < 16; ++j) {
        int idx = j * 256 + tid, kr = idx >> 6, c = idx & 63;
        Ws[c][kr]      = tob(Wk[(size_t)(kc + kr) * DKK + c]);
        Ws[64 + c][kr] = tob(Wv[(size_t)(kc + kr) * DKK + c]);
      }
      __syncthreads();
#pragma unroll
      for (int kk = 0; kk < 2; ++kk) {
        const float* ep = p.enc + (size_t)(b * 64 + w * 16 + l15) * DD + kc + kk * 32 + lhi * 8;
        short8 ae;
#pragma unroll
        for (int jj = 0; jj < 8; ++jj) { bf16 hb = tob(ep[jj]); ae[jj] = *(const short*)&hb; }
#pragma unroll
        for (int f = 0; f < 8; ++f) {
          short8 bfr = *(const short8*)&Ws[f * 16 + l15][kk * 32 + lhi * 8];
          acc[f] = __builtin_amdgcn_mfma_f32_16x16x32_bf16(ae, bfr, acc[f], 0, 0, 0);
        }
      }
    }
    const float* bk = p.ca_bk + i * DKK;
    const float* bv = p.ca_bv + i * DKK;
#pragma unroll
    for (int f = 0; f < 8; ++f) {
      int c = f * 16 + l15;
#pragma unroll
      for (int r = 0; r < 4; ++r) {
        int row = w * 16 + lhi * 4 + r;
        if (f < 4)
          p.kca[((size_t)i * BS + b * 64 + row) * DKK + c] = tob(acc[f][r] + bk[c]);
        else {
          int d = c - 64;
          p.vtca[(((size_t)i * 32 + b) * DKK + d) * 64 + row] = tob(acc[f][r] + bv[d]);
        }
      }
    }
    return;
  }

  const int bid = blockIdx.x - 128;
  float (*t)[33] = (float(*)[33])smem;
  const int tx = tid & 31, ty = tid >> 5;

  auto tr = [&](const float* src, int srcld, bf16* dst, int dstld, int n0, int k0) {
#pragma unroll
    for (int pp = 0; pp < 4; ++pp)
      t[ty + pp * 8][tx] = src[(size_t)(k0 + ty + pp * 8) * srcld + n0 + tx];
    __syncthreads();
#pragma unroll
    for (int pp = 0; pp < 4; ++pp)
      dst[(size_t)(n0 + ty + pp * 8) * dstld + k0 + tx] = tob(t[tx][ty + pp * 8]);
  };

  if (bid < 4096) {
    int z = bid >> 10, rem = bid & 1023, kb = rem >> 6, nb = rem & 63;
    tr(p.f_w1 + (size_t)z * DD * FF, FF, p.w1T + (size_t)z * FF * DD, DD, nb * 32, kb * 32);
  } else if (bid < 8192) {
    int q = bid - 4096;
    int z = q >> 10, rem = q & 1023, nb = rem & 15, kb = rem >> 4;
    tr(p.f_w2 + (size_t)z * FF * DD, DD, p.w2T + (size_t)z * DD * FF, FF, nb * 32, kb * 32);
  } else if (bid < 8960) {
    int q = bid - 8192;
    int z = q >> 5, rem = q & 31, nb = rem & 1, kb = rem >> 1;
    int side = z / 12, r2 = z % 12, i = r2 / 3, which = r2 % 3;
    int sel = side * 3 + which;
    const float* base = sel == 0 ? p.sa_wq : sel == 1 ? p.sa_wk : sel == 2 ? p.sa_wv
                      : sel == 3 ? p.ca_wq : sel == 4 ? p.ca_wk : p.ca_wv;
    bf16* dst = (side ? p.qkvTc : p.qkvTs) + (size_t)i * 192 * DD + (size_t)which * 64 * DD;
    tr(base + (size_t)i * DD * DKK, DKK, dst, DD, nb * 32, kb * 32);
  } else if (bid < 9216) {
    int q = bid - 8960;
    int z = q >> 5, rem = q & 31, nb = rem >> 1, kb = rem & 1;
    int side = z / LL, i = z % LL;
    const float* base = (side ? p.ca_wo : p.sa_wo) + (size_t)i * DKK * DD;
    bf16* dst = (side ? p.woTc : p.woTs) + (size_t)i * DD * DKK;
    tr(base, DD, dst, DKK, nb * 32, kb * 32);
  } else if (bid < 13312) {
    int i = (bid - 9216) * 256 + tid;
    p.encb[i] = tob(p.enc[i]);
  } else {
    int idx = (bid - 13312) * 256 + tid;
    int bs = idx / DD, d = idx % DD, s = bs % SS;
    float v = p.emb[(size_t)p.seq[bs] * DD + d] + p.pes[s * DD + d];
    p.x0[idx] = v;
    p.xb0[idx] = tob(v);
  }
}

// ================================================================ self-attention (reg-prefetched weights)
__global__ __launch_bounds__(256) void fused_attn_sa(
    const bf16* __restrict__ qin, const bf16* __restrict__ qkvT,
    const float* __restrict__ bq, const float* __restrict__ bk, const float* __restrict__ bv,
    const bf16* __restrict__ woT, const float* __restrict__ bo,
    const float* __restrict__ xres,
    const float* __restrict__ gamma, const float* __restrict__ beta,
    float* __restrict__ xout, bf16* __restrict__ xbout) {
  __shared__ bf16 Ws[192][72];
  __shared__ bf16 Qb[64][72], Kb[64][72], Vt[64][72], Pb[64][72], Hb[64][72];
  const int tid = threadIdx.x, w = tid >> 6, lane = tid & 63;
  const int l15 = lane & 15, lhi = lane >> 4;
  const int b = blockIdx.y, col0 = blockIdx.x * 128;
  const size_t abase = (size_t)(b * SS) * DD;

  short8 rw[6];
#pragma unroll
  for (int u = 0; u < 6; ++u) {
    int idx = u * 256 + tid, row = idx >> 3, c8 = idx & 7;
    rw[u] = *(const short8*)(qkvT + (size_t)row * DD + c8 * 8);
  }
  f32x4 acc[12] = {};
  for (int kc = 0; kc < DD; kc += 64) {
    __syncthreads();
#pragma unroll
    for (int u = 0; u < 6; ++u) {
      int idx = u * 256 + tid, row = idx >> 3, c8 = idx & 7;
      *(short8*)&Ws[row][c8 * 8] = rw[u];
    }
    if (kc + 64 < DD) {
#pragma unroll
      for (int u = 0; u < 6; ++u) {
        int idx = u * 256 + tid, row = idx >> 3, c8 = idx & 7;
        rw[u] = *(const short8*)(qkvT + (size_t)row * DD + kc + 64 + c8 * 8);
      }
    }
    __syncthreads();
#pragma unroll
    for (int kk = 0; kk < 2; ++kk) {
      short8 aq = *(const short8*)(qin + abase + (size_t)(w * 16 + l15) * DD + kc + kk * 32 + lhi * 8);
#pragma unroll
      for (int f = 0; f < 12; ++f) {
        short8 bfr = *(const short8*)&Ws[f * 16 + l15][kk * 32 + lhi * 8];
        acc[f] = __builtin_amdgcn_mfma_f32_16x16x32_bf16(aq, bfr, acc[f], 0, 0, 0);
      }
    }
  }
#pragma unroll
  for (int f = 0; f < 12; ++f) {
    int c = (f & 3) * 16 + l15;
#pragma unroll
    for (int r = 0; r < 4; ++r) {
      int row = w * 16 + lhi * 4 + r;
      if (f < 4)      Qb[row][c] = tob((acc[f][r] + bq[c]) * 0.125f);
      else if (f < 8) Kb[row][c] = tob(acc[f][r] + bk[c]);
      else            Vt[c][row] = tob(acc[f][r] + bv[c]);
    }
  }
  __syncthreads();

  f32x4 sacc[4] = {};
#pragma unroll
  for (int kk = 0; kk < 2; ++kk) {
    short8 aq = *(const short8*)&Qb[w * 16 + l15][kk * 32 + lhi * 8];
#pragma unroll
    for (int f = 0; f < 4; ++f) {
      short8 bfr = *(const short8*)&Kb[f * 16 + l15][kk * 32 + lhi * 8];
      sacc[f] = __builtin_amdgcn_mfma_f32_16x16x32_bf16(aq, bfr, sacc[f], 0, 0, 0);
    }
  }
#pragma unroll
  for (int r = 0; r < 4; ++r) {
    int qr = w * 16 + lhi * 4 + r;
    float sv[4], m = -3.0e38f;
#pragma unroll
    for (int f = 0; f < 4; ++f) {
      int kt = f * 16 + l15;
      bool valid = kt < qr;
      sv[f] = valid ? sacc[f][r] : -3.0e38f;
      m = fmaxf(m, sv[f]);
    }
#pragma unroll
    for (int off = 1; off < 16; off <<= 1) m = fmaxf(m, __shfl_xor(m, off));
    float pv[4], sum = 0.f;
#pragma unroll
    for (int f = 0; f < 4; ++f) {
      pv[f] = (sv[f] > -1.0e38f) ? __expf(sv[f] - m) : 0.f;
      sum += pv[f];
    }
#pragma unroll
    for (int off = 1; off < 16; off <<= 1) sum += __shfl_xor(sum, off);
    float rs = sum > 0.f ? 1.f / sum : 0.f;
#pragma unroll
    for (int f = 0; f < 4; ++f)
      Pb[qr][f * 16 + l15] = tob(pv[f] * rs);
  }
  __syncthreads();

  f32x4 hacc[4] = {};
#pragma unroll
  for (int kk = 0; kk < 2; ++kk) {
    short8 ap = *(const short8*)&Pb[w * 16 + l15][kk * 32 + lhi * 8];
#pragma unroll
    for (int f = 0; f < 4; ++f) {
      short8 bfr = *(const short8*)&Vt[f * 16 + l15][kk * 32 + lhi * 8];
      hacc[f] = __builtin_amdgcn_mfma_f32_16x16x32_bf16(ap, bfr, hacc[f], 0, 0, 0);
    }
  }
#pragma unroll
  for (int f = 0; f < 4; ++f)
#pragma unroll
    for (int r = 0; r < 4; ++r)
      Hb[w * 16 + lhi * 4 + r][f * 16 + l15] = tob(hacc[f][r]);
  __syncthreads();

  f32x4 oacc[8] = {};
#pragma unroll
  for (int kk = 0; kk < 2; ++kk) {
    short8 ah = *(const short8*)&Hb[w * 16 + l15][kk * 32 + lhi * 8];
#pragma unroll
    for (int f = 0; f < 8; ++f) {
      short8 bfr = *(const short8*)(woT + (size_t)(col0 + f * 16 + l15) * DKK + kk * 32 + lhi * 8);
      oacc[f] = __builtin_amdgcn_mfma_f32_16x16x32_bf16(ah, bfr, oacc[f], 0, 0, 0);
    }
  }
#pragma unroll
  for (int f = 0; f < 8; ++f) {
    int c = col0 + f * 16 + l15;
    float g = gamma[c], be = beta[c], bb = bo[c];
#pragma unroll
    for (int r = 0; r < 4; ++r) {
      int row = b * SS + w * 16 + lhi * 4 + r;
      float v = oacc[f][r] + bb;
      float res = xres[(size_t)row * DD + c] + v;
      float y = g * (res * BN_SCALE) + be;
      xout[(size_t)row * DD + c]  = y;
      xbout[(size_t)row * DD + c] = tob(y);
    }
  }
}

// ================================================================ cross-attention (hoisted K/V, reg-prefetch)
__global__ __launch_bounds__(256) void fused_attn_ca(
    const bf16* __restrict__ qin, const bf16* __restrict__ kca, const bf16* __restrict__ vtca,
    const bf16* __restrict__ qT, const float* __restrict__ bq,
    const bf16* __restrict__ woT, const float* __restrict__ bo,
    const float* __restrict__ xres,
    const float* __restrict__ gamma, const float* __restrict__ beta,
    float* __restrict__ xout, bf16* __restrict__ xbout) {
  __shared__ bf16 Ws[64][72];
  __shared__ bf16 Qb[64][72], Kb[64][72], Vt[64][72], Pb[64][72], Hb[64][72];
  const int tid = threadIdx.x, w = tid >> 6, lane = tid & 63;
  const int l15 = lane & 15, lhi = lane >> 4;
  const int b = blockIdx.y, col0 = blockIdx.x * 128;
  const size_t abase = (size_t)(b * SS) * DD;

#pragma unroll
  for (int v = 0; v < 2; ++v) {
    int idx = v * 256 + tid, r = idx >> 3, c8 = idx & 7;
    *(short8*)&Kb[r][c8 * 8] = *(const short8*)(kca + ((size_t)b * 64 + r) * DKK + c8 * 8);
    *(short8*)&Vt[r][c8 * 8] = *(const short8*)(vtca + ((size_t)b * DKK + r) * 64 + c8 * 8);
  }

  short8 rw[2];
#pragma unroll
  for (int u = 0; u < 2; ++u) {
    int idx = u * 256 + tid, row = idx >> 3, c8 = idx & 7;
    rw[u] = *(const short8*)(qT + (size_t)row * DD + c8 * 8);
  }
  f32x4 acc[4] = {};
  for (int kc = 0; kc < DD; kc += 64) {
    __syncthreads();
#pragma unroll
    for (int u = 0; u < 2; ++u) {
      int idx = u * 256 + tid, row = idx >> 3, c8 = idx & 7;
      *(short8*)&Ws[row][c8 * 8] = rw[u];
    }
    if (kc + 64 < DD) {
#pragma unroll
      for (int u = 0; u < 2; ++u) {
        int idx = u * 256 + tid, row = idx >> 3, c8 = idx & 7;
        rw[u] = *(const short8*)(qT + (size_t)row * DD + kc + 64 + c8 * 8);
      }
    }
    __syncthreads();
#pragma unroll
    for (int kk = 0; kk < 2; ++kk) {
      short8 aq = *(const short8*)(qin + abase + (size_t)(w * 16 + l15) * DD + kc + kk * 32 + lhi * 8);
#pragma unroll
      for (int f = 0; f < 4; ++f) {
        short8 bfr = *(const short8*)&Ws[f * 16 + l15][kk * 32 + lhi * 8];
        acc[f] = __builtin_amdgcn_mfma_f32_16x16x32_bf16(aq, bfr, acc[f], 0, 0, 0);
      }
    }
  }
#pragma unroll
  for (int f = 0; f < 4; ++f) {
    int c = f * 16 + l15;
#pragma unroll
    for (int r = 0; r < 4; ++r)
      Qb[w * 16 + lhi * 4 + r][c] = tob((acc[f][r] + bq[c]) * 0.125f);
  }
  __syncthreads();

  f32x4 sacc[4] = {};
#pragma unroll
  for (int kk = 0; kk < 2; ++kk) {
    short8 aq = *(const short8*)&Qb[w * 16 + l15][kk * 32 + lhi * 8];
#pragma unroll
    for (int f = 0; f < 4; ++f) {
      short8 bfr = *(const short8*)&Kb[f * 16 + l15][kk * 32 + lhi * 8];
      sacc[f] = __builtin_amdgcn_mfma_f32_16x16x32_bf16(aq, bfr, sacc[f], 0, 0, 0);
    }
  }
#pragma unroll
  for (int r = 0; r < 4; ++r) {
    int qr = w * 16 + lhi * 4 + r;
    float sv[4], m = -3.0e38f;
#pragma unroll
    for (int f = 0; f < 4; ++f) { sv[f] = sacc[f][r]; m = fmaxf(m, sv[f]); }
#pragma unroll
    for (int off = 1; off < 16; off <<= 1) m = fmaxf(m, __shfl_xor(m, off));
    float pv[4], sum = 0.f;
#pragma unroll
    for (int f = 0; f < 4; ++f) { pv[f] = __expf(sv[f] - m); sum += pv[f]; }
#pragma unroll
    for (int off = 1; off < 16; off <<= 1) sum += __shfl_xor(sum, off);
    float rs = 1.f / sum;
#pragma unroll
    for (int f = 0; f < 4; ++f)
      Pb[qr][f * 16 + l15] = tob(pv[f] * rs);
  }
  __syncthreads();

  f32x4 hacc[4] = {};
#pragma unroll
  for (int kk = 0; kk < 2; ++kk) {
    short8 ap = *(const short8*)&Pb[w * 16 + l15][kk * 32 + lhi * 8];
#pragma unroll
    for (int f = 0; f < 4; ++f) {
      short8 bfr = *(const short8*)&Vt[f * 16 + l15][kk * 32 + lhi * 8];
      hacc[f] = __builtin_amdgcn_mfma_f32_16x16x32_bf16(ap, bfr, hacc[f], 0, 0, 0);
    }
  }
#pragma unroll
  for (int f = 0; f < 4; ++f)
#pragma unroll
    for (int r = 0; r < 4; ++r)
      Hb[w * 16 + lhi * 4 + r][f * 16 + l15] = tob(hacc[f][r]);
  __syncthreads();

  f32x4 oacc[8] = {};
#pragma unroll
  for (int kk = 0; kk < 2; ++kk) {
    short8 ah = *(const short8*)&Hb[w * 16 + l15][kk * 32 + lhi * 8];
#pragma unroll
    for (int f = 0; f < 8; ++f) {
      short8 bfr = *(const short8*)(woT + (size_t)(col0 + f * 16 + l15) * DKK + kk * 32 + lhi * 8);
      oacc[f] = __builtin_amdgcn_mfma_f32_16x16x32_bf16(ah, bfr, oacc[f], 0, 0, 0);
    }
  }
#pragma unroll
  for (int f = 0; f < 8; ++f) {
    int c = col0 + f * 16 + l15;
    float g = gamma[c], be = beta[c], bb = bo[c];
#pragma unroll
    for (int r = 0; r < 4; ++r) {
      int row = b * SS + w * 16 + lhi * 4 + r;
      float v = oacc[f][r] + bb;
      float res = xres[(size_t)row * DD + c] + v;
      float y = g * (res * BN_SCALE) + be;
      xout[(size_t)row * DD + c]  = y;
      xbout[(size_t)row * DD + c] = tob(y);
    }
  }
}

// ================================================================ bf16 MFMA GEMM (gload_lds + dbuf, BK param)
template <int BM, int BN, int BK, int WM, int WN, int EPI>
__global__ __launch_bounds__(256) void mm_bf16(
    const bf16* __restrict__ A, const bf16* __restrict__ BT,
    int K, int N, const float* __restrict__ bias,
    bf16* __restrict__ outb, float* __restrict__ outf,
    const float* __restrict__ xres,
    const float* __restrict__ gamma, const float* __restrict__ beta) {
  constexpr int NA = BM * BK / 8 / 256;
  constexpr int NB = BN * BK / 8 / 256;
  constexpr int FM = BM / (WM * 16), FN = BN / (WN * 16);
  constexpr int M8 = BK / 8;             // short8 slots per row
  __shared__ __align__(16) bf16 As[2][BM * BK];
  __shared__ __align__(16) bf16 Bs[2][BN * BK];
  const int tid = threadIdx.x, lane = tid & 63, w = tid >> 6;
  const int wr = w / WN, wc = w % WN;
  const int l15 = lane & 15, lhi = lane >> 4;
  const int row0 = blockIdx.x * BM, col0 = blockIdx.y * BN;
  f32x4 acc[FM][FN] = {};

  auto stage = [&](int buf, int kc) {
#pragma unroll
    for (int c = 0; c < NA; ++c) {
      int j = c * 256 + tid, r = j / M8, c8 = j % M8;
      gload16(A + (size_t)(row0 + r) * K + kc + c8 * 8, &As[buf][(c * 256 + w * 64) * 8]);
    }
#pragma unroll
    for (int c = 0; c < NB; ++c) {
      int j = c * 256 + tid, r = j / M8, c8 = j % M8;
      gload16(BT + (size_t)(col0 + r) * K + kc + c8 * 8, &Bs[buf][(c * 256 + w * 64) * 8]);
    }
  };

  stage(0, 0);
  __syncthreads();
  const int NK = K / BK;
  for (int t = 0; t < NK; ++t) {
    int buf = t & 1;
    if (t + 1 < NK) stage(buf ^ 1, (t + 1) * BK);
#pragma unroll
    for (int kk = 0; kk < BK / 32; ++kk) {
      short8 af[FM], bfm[FN];
#pragma unroll
      for (int f = 0; f < FM; ++f)
        af[f] = *(const short8*)(&As[buf][(wr * FM * 16 + f * 16 + l15) * BK + kk * 32 + lhi * 8]);
#pragma unroll
      for (int f = 0; f < FN; ++f)
        bfm[f] = *(const short8*)(&Bs[buf][(wc * FN * 16 + f * 16 + l15) * BK + kk * 32 + lhi * 8]);
#pragma unroll
      for (int fm = 0; fm < FM; ++fm)
#pragma unroll
        for (int fn = 0; fn < FN; ++fn)
          acc[fm][fn] = __builtin_amdgcn_mfma_f32_16x16x32_bf16(af[fm], bfm[fn], acc[fm][fn], 0, 0, 0);
    }
    __syncthreads();
  }

#pragma unroll
  for (int fm = 0; fm < FM; ++fm)
#pragma unroll
    for (int r = 0; r < 4; ++r) {
      int row = row0 + wr * FM * 16 + fm * 16 + lhi * 4 + r;
#pragma unroll
      for (int fn = 0; fn < FN; ++fn) {
        int col = col0 + wc * FN * 16 + fn * 16 + l15;
        float v = acc[fm][fn][r] + bias[col];
        if (EPI == 1) {
          v = v > 0.f ? v : 0.f;
          outb[(size_t)row * N + col] = tob(v);
        } else {
          float sres = xres[(size_t)row * N + col] + v;
          float y = gamma[col] * (sres * BN_SCALE) + beta[col];
          outf[(size_t)row * N + col] = y;
          outb[(size_t)row * N + col] = tob(y);
        }
      }
    }
}

// ================================================================ final GEMM (R5-exact, KS=64)
__global__ __launch_bounds__(256) void fgemm_mfma(
    const bf16* __restrict__ flatb, const float* __restrict__ wout,
    float* __restrict__ fpart) {
  __shared__ float Ws[2][32][257];
  const int tid = threadIdx.x, lane = tid & 63, w = tid >> 6;
  const int l15 = lane & 15, lhi = lane >> 4;
  const int c0 = (blockIdx.x < 31) ? blockIdx.x * 256 : (VV - 256);
  const int k0 = blockIdx.y * FG_KCH;
  f32x4 acc[2][4] = {};

  auto stageW = [&](int buf, int it) {
    const float* src = wout + (size_t)(k0 + it * 32) * VV + c0;
#pragma unroll
    for (int i = 0; i < 8; ++i) {
      int row = i * 4 + w;
      gload16(src + (size_t)row * VV + lane * 4, &Ws[buf][row][0]);
    }
  };

  stageW(0, 0);
  __syncthreads();
  for (int it = 0; it < FG_KCH / 32; ++it) {
    int buf = it & 1;
    if (it + 1 < FG_KCH / 32) stageW(buf ^ 1, it + 1);
    short8 af[2];
#pragma unroll
    for (int mt = 0; mt < 2; ++mt)
      af[mt] = *(const short8*)(flatb + (size_t)(mt * 16 + l15) * (SS * DD) + k0 + it * 32 + lhi * 8);
#pragma unroll
    for (int ct = 0; ct < 4; ++ct) {
      int coll = w * 64 + ct * 16 + l15;
      short8 bfr;
#pragma unroll
      for (int jj = 0; jj < 8; ++jj) {
        bf16 hb = tob(Ws[buf][lhi * 8 + jj][coll]);
        bfr[jj] = *reinterpret_cast<const short*>(&hb);
      }
#pragma unroll
      for (int mt = 0; mt < 2; ++mt)
        acc[mt][ct] = __builtin_amdgcn_mfma_f32_16x16x32_bf16(af[mt], bfr, acc[mt][ct], 0, 0, 0);
    }
    __syncthreads();
  }

  float* pp = fpart + (size_t)blockIdx.y * 32 * VV;
#pragma unroll
  for (int mt = 0; mt < 2; ++mt)
#pragma unroll
    for (int ct = 0; ct < 4; ++ct)
#pragma unroll
      for (int r = 0; r < 4; ++r)
        pp[(size_t)(mt * 16 + lhi * 4 + r) * VV + c0 + w * 64 + ct * 16 + l15] = acc[mt][ct][r];
}

__global__ __launch_bounds__(256) void freduce(
    const float* __restrict__ fpart, const float* __restrict__ out_b,
    float* __restrict__ out) {
  int i = blockIdx.x * 256 + threadIdx.x;   // 256000 total
  int b = i / VV, c = i % VV;
  float s = out_b[c];
  for (int ks = 0; ks < FG_KS; ++ks)
    s += fpart[((size_t)ks * 32 + b) * VV + c];
  out[i] = s;
}

// ================================================================ launch (18 kernels)
extern "C" void kernel_launch(void* const* d_in, const int* in_sizes, int n_in,
                              void* d_out, int out_size, void* d_ws, size_t ws_size,
                              hipStream_t stream) {
  Params p;
  p.seq   = (const int*)  d_in[0];
  p.enc   = (const float*)d_in[1];
  p.pes   = (const float*)d_in[2];
  p.emb   = (const float*)d_in[3];
  p.sa_wq = (const float*)d_in[4];  p.sa_bq = (const float*)d_in[5];
  p.sa_wk = (const float*)d_in[6];  p.sa_bk = (const float*)d_in[7];
  p.sa_wv = (const float*)d_in[8];  p.sa_bv = (const float*)d_in[9];
  p.sa_wo = (const float*)d_in[10]; p.sa_bo = (const float*)d_in[11];
  p.ca_wq = (const float*)d_in[12]; p.ca_bq = (const float*)d_in[13];
  p.ca_wk = (const float*)d_in[14]; p.ca_bk = (const float*)d_in[15];
  p.ca_wv = (const float*)d_in[16]; p.ca_bv = (const float*)d_in[17];
  p.ca_wo = (const float*)d_in[18]; p.ca_bo = (const float*)d_in[19];
  p.f_w1  = (const float*)d_in[20]; p.f_b1  = (const float*)d_in[21];
  p.f_w2  = (const float*)d_in[22]; p.f_b2  = (const float*)d_in[23];
  p.bn_g  = (const float*)d_in[24]; p.bn_b  = (const float*)d_in[25];
  p.out_w = (const float*)d_in[26]; p.out_b = (const float*)d_in[27];
  p.out = (float*)d_out;

  char* wp = (char*)d_ws;
  size_t off = 0;
  auto alloc = [&](size_t bytes) { void* q = wp + off; off += (bytes + 255) & ~(size_t)255; return q; };
  p.x0  = (float*)alloc((size_t)BS * DD * 4);
  p.x1  = (float*)alloc((size_t)BS * DD * 4);
  p.xb0 = (bf16*)alloc((size_t)BS * DD * 2);
  p.xb1 = (bf16*)alloc((size_t)BS * DD * 2);
  p.h   = (bf16*)alloc((size_t)BS * FF * 2);
  p.w1T = (bf16*)alloc((size_t)LL * DD * FF * 2);
  p.w2T = (bf16*)alloc((size_t)LL * DD * FF * 2);
  p.qkvTs = (bf16*)alloc((size_t)LL * 192 * DD * 2);
  p.qkvTc = (bf16*)alloc((size_t)LL * 192 * DD * 2);
  p.woTs  = (bf16*)alloc((size_t)LL * DD * DKK * 2);
  p.woTc  = (bf16*)alloc((size_t)LL * DD * DKK * 2);
  p.encb  = (bf16*)alloc((size_t)32 * SS * DD * 2);
  p.kca   = (bf16*)alloc((size_t)LL * BS * DKK * 2);
  p.vtca  = (bf16*)alloc((size_t)LL * BS * DKK * 2);
  p.fpart = (float*)alloc((size_t)FG_KS * 32 * VV * 4);

  prep_kernel<<<17536, 256, 0, stream>>>(p);

  float* xc = p.x0; float* xa = p.x1;
  bf16* xbc = p.xb0; bf16* xba = p.xb1;

  for (int i = 0; i < LL; ++i) {
    const float* g0  = p.bn_g + (size_t)(i * 3 + 0) * DD;
    const float* be0 = p.bn_b + (size_t)(i * 3 + 0) * DD;
    const float* g1  = p.bn_g + (size_t)(i * 3 + 1) * DD;
    const float* be1 = p.bn_b + (size_t)(i * 3 + 1) * DD;
    const float* g2  = p.bn_g + (size_t)(i * 3 + 2) * DD;
    const float* be2 = p.bn_b + (size_t)(i * 3 + 2) * DD;

    fused_attn_sa<<<dim3(4, 32), 256, 0, stream>>>(
        xbc, p.qkvTs + (size_t)i * 192 * DD,
        p.sa_bq + i * DKK, p.sa_bk + i * DKK, p.sa_bv + i * DKK,
        p.woTs + (size_t)i * DD * DKK, p.sa_bo + (size_t)i * DD,
        xc, g0, be0, xa, xba);
    fused_attn_ca<<<dim3(4, 32), 256, 0, stream>>>(
        xba, p.kca + (size_t)i * BS * DKK, p.vtca + (size_t)i * BS * DKK,
        p.qkvTc + (size_t)i * 192 * DD, p.ca_bq + i * DKK,
        p.woTc + (size_t)i * DD * DKK, p.ca_bo + (size_t)i * DD,
        xa, g1, be1, xc, xbc);
    mm_bf16<128, 128, 128, 2, 2, 1><<<dim3(16, 16), 256, 0, stream>>>(
        xbc, p.w1T + (size_t)i * DD * FF, DD, FF, p.f_b1 + (size_t)i * FF,
        p.h, nullptr, nullptr, nullptr, nullptr);
    mm_bf16<64, 64, 128, 2, 2, 2><<<dim3(32, 8), 256, 0, stream>>>(
        p.h, p.w2T + (size_t)i * DD * FF, FF, DD, p.f_b2 + (size_t)i * DD,
        xba, xa, xc, g2, be2);

    { float* t = xc; xc = xa; xa = t; }
    { bf16* t = xbc; xbc = xba; xba = t; }
  }

  fgemm_mfma<<<dim3(32, FG_KS), 256, 0, stream>>>(xbc, p.out_w, p.fpart);
  freduce<<<1000, 256, 0, stream>>>(p.fpart, p.out_b, p.out);
}

// Round 12
// 549.513 us; speedup vs baseline: 1.0994x; 1.0994x over previous
//
#include <hip/hip_runtime.h>
#include <hip/hip_bf16.h>
#include <cstddef>

#define DD 512
#define DKK 64
#define SS 64
#define BS 2048
#define FF 2048
#define VV 8000
#define LL 4
#define BN_SCALE 0.9995003746f
#define FG_KS 64
#define FG_KCH 512

typedef __attribute__((ext_vector_type(8))) short short8;
typedef __attribute__((ext_vector_type(4))) float f32x4;
typedef __hip_bfloat16 bf16;

__device__ __forceinline__ void gload16(const void* g, void* l) {
  __builtin_amdgcn_global_load_lds((const __attribute__((address_space(1))) void*)g,
                                   (__attribute__((address_space(3))) void*)l, 16, 0, 0);
}
__device__ __forceinline__ bf16 tob(float v) { return __float2bfloat16(v); }

// ---------------------------------------------------------------- merged preprocessing
// sections: [0,4096) w1T ; [4096,8192) w2T ; [8192,8960) qkvT ; [8960,9216) woT ;
//           [9216,13312) enc->bf16 ; [13312,17408) embed
__global__ __launch_bounds__(256) void prep_kernel(
    const float* __restrict__ f_w1, const float* __restrict__ f_w2,
    const float* __restrict__ sa_wq, const float* __restrict__ sa_wk, const float* __restrict__ sa_wv,
    const float* __restrict__ ca_wq, const float* __restrict__ ca_wk, const float* __restrict__ ca_wv,
    const float* __restrict__ sa_wo, const float* __restrict__ ca_wo,
    const float* __restrict__ enc, const int* __restrict__ seq,
    const float* __restrict__ emb, const float* __restrict__ pes,
    bf16* __restrict__ w1T, bf16* __restrict__ w2T,
    bf16* __restrict__ qkvTs, bf16* __restrict__ qkvTc,
    bf16* __restrict__ woTs, bf16* __restrict__ woTc,
    bf16* __restrict__ encb, float* __restrict__ x, bf16* __restrict__ xb) {
  __shared__ float t[32][33];
  const int bid = blockIdx.x;
  const int tid = threadIdx.x;
  const int tx = tid & 31, ty = tid >> 5;

  auto tr = [&](const float* src, int srcld, bf16* dst, int dstld, int n0, int k0) {
#pragma unroll
    for (int p = 0; p < 4; ++p)
      t[ty + p * 8][tx] = src[(size_t)(k0 + ty + p * 8) * srcld + n0 + tx];
    __syncthreads();
#pragma unroll
    for (int p = 0; p < 4; ++p)
      dst[(size_t)(n0 + ty + p * 8) * dstld + k0 + tx] = tob(t[tx][ty + p * 8]);
  };

  if (bid < 4096) {                       // w1: [L][512][2048] -> [L][2048][512]
    int z = bid >> 10, rem = bid & 1023, kb = rem >> 6, nb = rem & 63;
    tr(f_w1 + (size_t)z * DD * FF, FF, w1T + (size_t)z * FF * DD, DD, nb * 32, kb * 32);
  } else if (bid < 8192) {                // w2: [L][2048][512] -> [L][512][2048]
    int q = bid - 4096;
    int z = q >> 10, rem = q & 1023, nb = rem & 15, kb = rem >> 4;
    tr(f_w2 + (size_t)z * FF * DD, DD, w2T + (size_t)z * DD * FF, FF, nb * 32, kb * 32);
  } else if (bid < 8960) {                // qkv: [512][64] -> rows of [192][512]
    int q = bid - 8192;
    int z = q >> 5, rem = q & 31, nb = rem & 1, kb = rem >> 1;
    int side = z / 12, r2 = z % 12, i = r2 / 3, which = r2 % 3;
    int sel = side * 3 + which;
    const float* base = sel == 0 ? sa_wq : sel == 1 ? sa_wk : sel == 2 ? sa_wv
                      : sel == 3 ? ca_wq : sel == 4 ? ca_wk : ca_wv;
    bf16* dst = (side ? qkvTc : qkvTs) + (size_t)i * 192 * DD + (size_t)which * 64 * DD;
    tr(base + (size_t)i * DD * DKK, DKK, dst, DD, nb * 32, kb * 32);
  } else if (bid < 9216) {                // wo: [64][512] -> [512][64]
    int q = bid - 8960;
    int z = q >> 5, rem = q & 31, nb = rem >> 1, kb = rem & 1;
    int side = z / LL, i = z % LL;
    const float* base = (side ? ca_wo : sa_wo) + (size_t)i * DKK * DD;
    bf16* dst = (side ? woTc : woTs) + (size_t)i * DD * DKK;
    tr(base, DD, dst, DKK, nb * 32, kb * 32);
  } else if (bid < 13312) {               // enc -> bf16
    int i = (bid - 9216) * 256 + tid;
    encb[i] = tob(enc[i]);
  } else {                                // embedding
    int idx = (bid - 13312) * 256 + tid;
    int bs = idx / DD, d = idx % DD, s = bs % SS;
    float v = emb[(size_t)seq[bs] * DD + d] + pes[s * DD + d];
    x[idx]  = v;
    xb[idx] = tob(v);
  }
}

// ---------------------------------------------------------------- fused attention block
template <bool CAUSAL>
__global__ __launch_bounds__(256) void fused_attn(
    const bf16* __restrict__ qin,
    const bf16* __restrict__ kvin,
    const bf16* __restrict__ qkvT,
    const float* __restrict__ bq, const float* __restrict__ bk, const float* __restrict__ bv,
    const bf16* __restrict__ woT,
    const float* __restrict__ bo,
    const float* __restrict__ xres,
    const float* __restrict__ gamma, const float* __restrict__ beta,
    float* __restrict__ xout, bf16* __restrict__ xbout) {
  __shared__ bf16 Ws[192][72];
  __shared__ bf16 Qb[64][72], Kb[64][72], Vt[64][72], Pb[64][72], Hb[64][72];
  const int tid  = threadIdx.x;
  const int w    = tid >> 6;
  const int lane = tid & 63;
  const int l15  = lane & 15, lhi = lane >> 4;
  const int b    = blockIdx.y;
  const int col0 = blockIdx.x * 128;
  const size_t abase = (size_t)(b * SS) * DD;

  // ---- phase A: Q,K,V = [X | Xkv] @ Wqkv
  f32x4 acc[12] = {};
  for (int kc = 0; kc < DD; kc += 64) {
    __syncthreads();
#pragma unroll
    for (int u = 0; u < 6; ++u) {
      int idx = u * 256 + tid; int row = idx >> 3; int c8 = idx & 7;
      *(short8*)&Ws[row][c8 * 8] = *(const short8*)(qkvT + (size_t)row * DD + kc + c8 * 8);
    }
    __syncthreads();
#pragma unroll
    for (int kk = 0; kk < 2; ++kk) {
      short8 aq  = *(const short8*)(qin  + abase + (size_t)(w * 16 + l15) * DD + kc + kk * 32 + lhi * 8);
      short8 akv = *(const short8*)(kvin + abase + (size_t)(w * 16 + l15) * DD + kc + kk * 32 + lhi * 8);
#pragma unroll
      for (int f = 0; f < 12; ++f) {
        short8 bfr = *(const short8*)&Ws[f * 16 + l15][kk * 32 + lhi * 8];
        acc[f] = __builtin_amdgcn_mfma_f32_16x16x32_bf16(f < 4 ? aq : akv, bfr, acc[f], 0, 0, 0);
      }
    }
  }
#pragma unroll
  for (int f = 0; f < 12; ++f) {
    int c = (f & 3) * 16 + l15;
#pragma unroll
    for (int r = 0; r < 4; ++r) {
      int row = w * 16 + lhi * 4 + r;
      if (f < 4)      Qb[row][c] = tob((acc[f][r] + bq[c]) * 0.125f);
      else if (f < 8) Kb[row][c] = tob(acc[f][r] + bk[c]);
      else            Vt[c][row] = tob(acc[f][r] + bv[c]);
    }
  }
  __syncthreads();

  // ---- phase B: S = Q @ K^T + softmax
  f32x4 sacc[4] = {};
#pragma unroll
  for (int kk = 0; kk < 2; ++kk) {
    short8 aq = *(const short8*)&Qb[w * 16 + l15][kk * 32 + lhi * 8];
#pragma unroll
    for (int f = 0; f < 4; ++f) {
      short8 bfr = *(const short8*)&Kb[f * 16 + l15][kk * 32 + lhi * 8];
      sacc[f] = __builtin_amdgcn_mfma_f32_16x16x32_bf16(aq, bfr, sacc[f], 0, 0, 0);
    }
  }
#pragma unroll
  for (int r = 0; r < 4; ++r) {
    int qr = w * 16 + lhi * 4 + r;
    float sv[4];
    float m = -3.0e38f;
#pragma unroll
    for (int f = 0; f < 4; ++f) {
      int kt = f * 16 + l15;
      bool valid = (!CAUSAL) || (kt < qr);
      sv[f] = valid ? sacc[f][r] : -3.0e38f;
      m = fmaxf(m, sv[f]);
    }
#pragma unroll
    for (int off = 1; off < 16; off <<= 1) m = fmaxf(m, __shfl_xor(m, off));
    float pv[4], sum = 0.f;
#pragma unroll
    for (int f = 0; f < 4; ++f) {
      pv[f] = (sv[f] > -1.0e38f) ? __expf(sv[f] - m) : 0.f;
      sum += pv[f];
    }
#pragma unroll
    for (int off = 1; off < 16; off <<= 1) sum += __shfl_xor(sum, off);
    float rs = sum > 0.f ? 1.f / sum : 0.f;
#pragma unroll
    for (int f = 0; f < 4; ++f)
      Pb[qr][f * 16 + l15] = tob(pv[f] * rs);
  }
  __syncthreads();

  // ---- phase C: head = P @ V
  f32x4 hacc[4] = {};
#pragma unroll
  for (int kk = 0; kk < 2; ++kk) {
    short8 ap = *(const short8*)&Pb[w * 16 + l15][kk * 32 + lhi * 8];
#pragma unroll
    for (int f = 0; f < 4; ++f) {
      short8 bfr = *(const short8*)&Vt[f * 16 + l15][kk * 32 + lhi * 8];
      hacc[f] = __builtin_amdgcn_mfma_f32_16x16x32_bf16(ap, bfr, hacc[f], 0, 0, 0);
    }
  }
#pragma unroll
  for (int f = 0; f < 4; ++f)
#pragma unroll
    for (int r = 0; r < 4; ++r)
      Hb[w * 16 + lhi * 4 + r][f * 16 + l15] = tob(hacc[f][r]);
  __syncthreads();

  // ---- phase D: out = head @ Wo + bo, +residual, BN
  f32x4 oacc[8] = {};
#pragma unroll
  for (int kk = 0; kk < 2; ++kk) {
    short8 ah = *(const short8*)&Hb[w * 16 + l15][kk * 32 + lhi * 8];
#pragma unroll
    for (int f = 0; f < 8; ++f) {
      short8 bfr = *(const short8*)(woT + (size_t)(col0 + f * 16 + l15) * DKK + kk * 32 + lhi * 8);
      oacc[f] = __builtin_amdgcn_mfma_f32_16x16x32_bf16(ah, bfr, oacc[f], 0, 0, 0);
    }
  }
#pragma unroll
  for (int f = 0; f < 8; ++f) {
    int c = col0 + f * 16 + l15;
    float g = gamma[c], be = beta[c], bb = bo[c];
#pragma unroll
    for (int r = 0; r < 4; ++r) {
      int row = b * SS + w * 16 + lhi * 4 + r;
      float v = oacc[f][r] + bb;
      float res = xres[(size_t)row * DD + c] + v;
      float y = g * (res * BN_SCALE) + be;
      xout[(size_t)row * DD + c]  = y;
      xbout[(size_t)row * DD + c] = tob(y);
    }
  }
}

// ---------------------------------------------------------------- bf16 MFMA GEMM (gload_lds + dbuf)
template <int BM, int BN, int WM, int WN, int EPI>
__global__ __launch_bounds__(256) void mm_bf16(
    const bf16* __restrict__ A, const bf16* __restrict__ BT,
    int K, int N, const float* __restrict__ bias,
    bf16* __restrict__ outb, float* __restrict__ outf,
    const float* __restrict__ xres,
    const float* __restrict__ gamma, const float* __restrict__ beta) {
  constexpr int NA = BM * 64 / 8 / 256;
  constexpr int NB = BN * 64 / 8 / 256;
  constexpr int FM = BM / (WM * 16), FN = BN / (WN * 16);
  __shared__ __align__(16) bf16 As[2][BM * 64];
  __shared__ __align__(16) bf16 Bs[2][BN * 64];
  const int tid = threadIdx.x, lane = tid & 63, w = tid >> 6;
  const int wr = w / WN, wc = w % WN;
  const int l15 = lane & 15, lhi = lane >> 4;
  const int row0 = blockIdx.x * BM, col0 = blockIdx.y * BN;
  f32x4 acc[FM][FN] = {};

  auto stage = [&](int buf, int kc) {
#pragma unroll
    for (int c = 0; c < NA; ++c) {
      int j = c * 256 + tid;
      int r = j >> 3, c8 = j & 7;
      gload16(A + (size_t)(row0 + r) * K + kc + c8 * 8,
              &As[buf][(c * 256 + w * 64) * 8]);
    }
#pragma unroll
    for (int c = 0; c < NB; ++c) {
      int j = c * 256 + tid;
      int r = j >> 3, c8 = j & 7;
      gload16(BT + (size_t)(col0 + r) * K + kc + c8 * 8,
              &Bs[buf][(c * 256 + w * 64) * 8]);
    }
  };

  stage(0, 0);
  __syncthreads();
  const int NK = K / 64;
  for (int t = 0; t < NK; ++t) {
    int buf = t & 1;
    if (t + 1 < NK) stage(buf ^ 1, (t + 1) * 64);
#pragma unroll
    for (int kk = 0; kk < 2; ++kk) {
      short8 af[FM], bfm[FN];
#pragma unroll
      for (int f = 0; f < FM; ++f)
        af[f] = *(const short8*)(&As[buf][(wr * FM * 16 + f * 16 + l15) * 64 + kk * 32 + lhi * 8]);
#pragma unroll
      for (int f = 0; f < FN; ++f)
        bfm[f] = *(const short8*)(&Bs[buf][(wc * FN * 16 + f * 16 + l15) * 64 + kk * 32 + lhi * 8]);
#pragma unroll
      for (int fm = 0; fm < FM; ++fm)
#pragma unroll
        for (int fn = 0; fn < FN; ++fn)
          acc[fm][fn] = __builtin_amdgcn_mfma_f32_16x16x32_bf16(af[fm], bfm[fn], acc[fm][fn], 0, 0, 0);
    }
    __syncthreads();
  }

#pragma unroll
  for (int fm = 0; fm < FM; ++fm)
#pragma unroll
    for (int r = 0; r < 4; ++r) {
      int row = row0 + wr * FM * 16 + fm * 16 + lhi * 4 + r;
#pragma unroll
      for (int fn = 0; fn < FN; ++fn) {
        int col = col0 + wc * FN * 16 + fn * 16 + l15;
        float v = acc[fm][fn][r] + bias[col];
        if (EPI == 1) {
          v = v > 0.f ? v : 0.f;
          outb[(size_t)row * N + col] = tob(v);
        } else {
          float sres = xres[(size_t)row * N + col] + v;
          float y = gamma[col] * (sres * BN_SCALE) + beta[col];
          outf[(size_t)row * N + col] = y;
          outb[(size_t)row * N + col] = tob(y);
        }
      }
    }
}

// ---------------------------------------------------------------- final GEMM: MFMA, on-the-fly W->bf16
__global__ __launch_bounds__(256) void fgemm_mfma(
    const bf16* __restrict__ flatb, const float* __restrict__ wout,
    float* __restrict__ fpart) {
  __shared__ float Ws[2][32][257];          // pad 257: 2-way bank aliasing (free)
  const int tid = threadIdx.x, lane = tid & 63, w = tid >> 6;
  const int l15 = lane & 15, lhi = lane >> 4;
  const int c0 = (blockIdx.x < 31) ? blockIdx.x * 256 : (VV - 256);  // overlap dup-writes: benign
  const int k0 = blockIdx.y * FG_KCH;
  f32x4 acc[2][4] = {};

  auto stageW = [&](int buf, int it) {
    const float* src = wout + (size_t)(k0 + it * 32) * VV + c0;
#pragma unroll
    for (int i = 0; i < 8; ++i) {
      int row = i * 4 + w;                  // one full 256-col row per wave-inst
      gload16(src + (size_t)row * VV + lane * 4, &Ws[buf][row][0]);
    }
  };

  stageW(0, 0);
  __syncthreads();
  for (int it = 0; it < 16; ++it) {
    int buf = it & 1;
    if (it + 1 < 16) stageW(buf ^ 1, it + 1);
    short8 af[2];
#pragma unroll
    for (int mt = 0; mt < 2; ++mt)
      af[mt] = *(const short8*)(flatb + (size_t)(mt * 16 + l15) * (SS * DD) + k0 + it * 32 + lhi * 8);
#pragma unroll
    for (int ct = 0; ct < 4; ++ct) {
      int coll = w * 64 + ct * 16 + l15;
      short8 bfr;
#pragma unroll
      for (int j = 0; j < 8; ++j) {
        bf16 hb = tob(Ws[buf][lhi * 8 + j][coll]);
        bfr[j] = *reinterpret_cast<const short*>(&hb);
      }
#pragma unroll
      for (int mt = 0; mt < 2; ++mt)
        acc[mt][ct] = __builtin_amdgcn_mfma_f32_16x16x32_bf16(af[mt], bfr, acc[mt][ct], 0, 0, 0);
    }
    __syncthreads();
  }

  float* pp = fpart + (size_t)blockIdx.y * 32 * VV;
#pragma unroll
  for (int mt = 0; mt < 2; ++mt)
#pragma unroll
    for (int ct = 0; ct < 4; ++ct)
#pragma unroll
      for (int r = 0; r < 4; ++r)
        pp[(size_t)(mt * 16 + lhi * 4 + r) * VV + c0 + w * 64 + ct * 16 + l15] = acc[mt][ct][r];
}

__global__ __launch_bounds__(256) void freduce(
    const float* __restrict__ fpart, const float* __restrict__ out_b,
    float* __restrict__ out) {
  int i = blockIdx.x * 256 + threadIdx.x;   // 256000 total
  int b = i / VV, c = i % VV;
  float s = out_b[c];
  for (int ks = 0; ks < FG_KS; ++ks)
    s += fpart[((size_t)ks * 32 + b) * VV + c];
  out[i] = s;
}

// ---------------------------------------------------------------- launch
extern "C" void kernel_launch(void* const* d_in, const int* in_sizes, int n_in,
                              void* d_out, int out_size, void* d_ws, size_t ws_size,
                              hipStream_t stream) {
  const int*   seq   = (const int*)  d_in[0];
  const float* enc   = (const float*)d_in[1];
  const float* pes   = (const float*)d_in[2];
  const float* emb   = (const float*)d_in[3];
  const float* sa_wq = (const float*)d_in[4];
  const float* sa_bq = (const float*)d_in[5];
  const float* sa_wk = (const float*)d_in[6];
  const float* sa_bk = (const float*)d_in[7];
  const float* sa_wv = (const float*)d_in[8];
  const float* sa_bv = (const float*)d_in[9];
  const float* sa_wo = (const float*)d_in[10];
  const float* sa_bo = (const float*)d_in[11];
  const float* ca_wq = (const float*)d_in[12];
  const float* ca_bq = (const float*)d_in[13];
  const float* ca_wk = (const float*)d_in[14];
  const float* ca_bk = (const float*)d_in[15];
  const float* ca_wv = (const float*)d_in[16];
  const float* ca_bv = (const float*)d_in[17];
  const float* ca_wo = (const float*)d_in[18];
  const float* ca_bo = (const float*)d_in[19];
  const float* f_w1  = (const float*)d_in[20];
  const float* f_b1  = (const float*)d_in[21];
  const float* f_w2  = (const float*)d_in[22];
  const float* f_b2  = (const float*)d_in[23];
  const float* bn_g  = (const float*)d_in[24];
  const float* bn_b  = (const float*)d_in[25];
  const float* out_w = (const float*)d_in[26];
  const float* out_b = (const float*)d_in[27];
  float* out = (float*)d_out;

  char* wp = (char*)d_ws;
  size_t off = 0;
  auto alloc = [&](size_t bytes) { void* q = wp + off; off += (bytes + 255) & ~(size_t)255; return q; };
  float* x0 = (float*)alloc((size_t)BS * DD * 4);
  float* x1 = (float*)alloc((size_t)BS * DD * 4);
  bf16* xb0 = (bf16*)alloc((size_t)BS * DD * 2);
  bf16* xb1 = (bf16*)alloc((size_t)BS * DD * 2);
  bf16* h   = (bf16*)alloc((size_t)BS * FF * 2);
  bf16* w1T = (bf16*)alloc((size_t)LL * DD * FF * 2);
  bf16* w2T = (bf16*)alloc((size_t)LL * DD * FF * 2);
  bf16* qkvTs = (bf16*)alloc((size_t)LL * 192 * DD * 2);
  bf16* qkvTc = (bf16*)alloc((size_t)LL * 192 * DD * 2);
  bf16* woTs  = (bf16*)alloc((size_t)LL * DD * DKK * 2);
  bf16* woTc  = (bf16*)alloc((size_t)LL * DD * DKK * 2);
  bf16* encb  = (bf16*)alloc((size_t)32 * SS * DD * 2);
  float* fpart = (float*)alloc((size_t)FG_KS * 32 * VV * 4);

  // ---- single preprocessing launch
  prep_kernel<<<17408, 256, 0, stream>>>(
      f_w1, f_w2, sa_wq, sa_wk, sa_wv, ca_wq, ca_wk, ca_wv, sa_wo, ca_wo,
      enc, seq, emb, pes,
      w1T, w2T, qkvTs, qkvTc, woTs, woTc, encb, x0, xb0);

  float* xc = x0; float* xa = x1;
  bf16* xbc = xb0; bf16* xba = xb1;

  for (int i = 0; i < LL; ++i) {
    const float* g0  = bn_g + (size_t)(i * 3 + 0) * DD;
    const float* be0 = bn_b + (size_t)(i * 3 + 0) * DD;
    const float* g1  = bn_g + (size_t)(i * 3 + 1) * DD;
    const float* be1 = bn_b + (size_t)(i * 3 + 1) * DD;
    const float* g2  = bn_g + (size_t)(i * 3 + 2) * DD;
    const float* be2 = bn_b + (size_t)(i * 3 + 2) * DD;

    // self-attn: reads xc/xbc -> writes xa/xba
    fused_attn<true><<<dim3(4, 32), 256, 0, stream>>>(
        xbc, xbc, qkvTs + (size_t)i * 192 * DD,
        sa_bq + i * DKK, sa_bk + i * DKK, sa_bv + i * DKK,
        woTs + (size_t)i * DD * DKK, sa_bo + (size_t)i * DD,
        xc, g0, be0, xa, xba);
    // cross-attn: reads xa/xba (q), encb (kv) -> writes xc/xbc
    fused_attn<false><<<dim3(4, 32), 256, 0, stream>>>(
        xba, encb, qkvTc + (size_t)i * 192 * DD,
        ca_bq + i * DKK, ca_bk + i * DKK, ca_bv + i * DKK,
        woTc + (size_t)i * DD * DKK, ca_bo + (size_t)i * DD,
        xa, g1, be1, xc, xbc);
    // FFN
    mm_bf16<128, 128, 2, 2, 1><<<dim3(16, 16), 256, 0, stream>>>(
        xbc, w1T + (size_t)i * DD * FF, DD, FF, f_b1 + (size_t)i * FF,
        h, nullptr, nullptr, nullptr, nullptr);
    mm_bf16<64, 64, 2, 2, 2><<<dim3(32, 8), 256, 0, stream>>>(
        h, w2T + (size_t)i * DD * FF, FF, DD, f_b2 + (size_t)i * DD,
        xba, xa, xc, g2, be2);

    { float* t = xc; xc = xa; xa = t; }
    { bf16* t = xbc; xbc = xba; xba = t; }
  }

  fgemm_mfma<<<dim3(32, FG_KS), 256, 0, stream>>>(xbc, out_w, fpart);
  freduce<<<1000, 256, 0, stream>>>(fpart, out_b, out);
}